// Round 1
// baseline (145.810 us; speedup 1.0000x reference)
//
#include <hip/hip_runtime.h>

// Reference collapse (forward value):
//   c = y[b]
//   k = argmax_k ( logits[c,k] + gumbel[c,b,k] )   (first max wins)
//   x[b,j] = m[c,k,j] + sum_i z[b,i] * L[c,k,j,i]
//
// Shapes: z (BS,128) f32 | y (BS,) int | gumbel (10,BS,10) f32
//         m (10,10,128) f32 | L (10,10,128,128) f32 | logits (10,10) f32
// Output: x (BS,128) f32

#define N_Z 128
#define N_COMP 10
#define N_CLASSES 10

__global__ __launch_bounds__(128) void gmm_select_matvec(
    const float* __restrict__ z,
    const int* __restrict__ y,
    const float* __restrict__ gumbel,
    const float* __restrict__ m,
    const float* __restrict__ L,
    const float* __restrict__ logits,
    float* __restrict__ out,
    int bs)
{
    const int b = blockIdx.x;
    const int j = threadIdx.x;  // 0..127, one output element per thread

    __shared__ float zs[N_Z];
    __shared__ int ck_sel;

    // stage z row
    zs[j] = z[(size_t)b * N_Z + j];

    // thread 0: class lookup + 10-way argmax of logits[c,:] + gumbel[c,b,:]
    if (j == 0) {
        const int c = y[b];
        const float* g  = gumbel + ((size_t)c * bs + b) * N_COMP;
        const float* lg = logits + c * N_COMP;
        float best = g[0] + lg[0];
        int   bi   = 0;
        #pragma unroll
        for (int k = 1; k < N_COMP; ++k) {
            float s = g[k] + lg[k];
            if (s > best) { best = s; bi = k; }  // strict > keeps first-max (jnp.argmax)
        }
        ck_sel = c * N_COMP + bi;
    }
    __syncthreads();

    const int ck = ck_sel;
    const float* Lrow = L + ((size_t)ck * N_Z + j) * N_Z;  // row j of selected 128x128 matrix
    float acc = m[(size_t)ck * N_Z + j];

    #pragma unroll
    for (int i = 0; i < N_Z; i += 4) {
        float4 lv = *(const float4*)(Lrow + i);
        acc += lv.x * zs[i] + lv.y * zs[i + 1] + lv.z * zs[i + 2] + lv.w * zs[i + 3];
    }

    out[(size_t)b * N_Z + j] = acc;
}

extern "C" void kernel_launch(void* const* d_in, const int* in_sizes, int n_in,
                              void* d_out, int out_size, void* d_ws, size_t ws_size,
                              hipStream_t stream)
{
    const float* z      = (const float*)d_in[0];
    const int*   y      = (const int*)d_in[1];
    const float* gumbel = (const float*)d_in[2];
    const float* m      = (const float*)d_in[3];
    const float* L      = (const float*)d_in[4];
    const float* logits = (const float*)d_in[5];
    float* out = (float*)d_out;

    const int bs = in_sizes[0] / N_Z;  // 8192

    gmm_select_matvec<<<bs, N_Z, 0, stream>>>(z, y, gumbel, m, L, logits, out, bs);
}

// Round 3
// 114.269 us; speedup vs baseline: 1.2760x; 1.2760x over previous
//
#include <hip/hip_runtime.h>

// Forward collapse:
//   c = y[b]; k = argmax_k(logits[c,k] + gumbel[c,b,k]) (first max)
//   x[b,:] = L[c,k] @ z[b,:] + m[c,k,:]
//
// Strategy: counting-sort samples by ck = c*10+k (100 buckets, ~82 samples each),
// then one register-tiled batched-GEMV block per (ck, j-half, 64-sample chunk).
// L[ck] is read once per active block instead of once per sample.

#define N_Z 128
#define N_COMP 10
#define N_CLASSES 10
#define N_CK (N_CLASSES * N_COMP)
#define TB 64            // samples per chunk in gemm kernel
#define MAXCHUNK 4       // supports buckets up to 256 samples (~19 sigma)

// ---------------- K1: per-sample component select + histogram ----------------
__global__ __launch_bounds__(256) void k_select(
    const int* __restrict__ y, const float* __restrict__ gumbel,
    const float* __restrict__ logits, int* __restrict__ ck_arr,
    int* __restrict__ counts, int bs)
{
    int b = blockIdx.x * 256 + threadIdx.x;
    if (b >= bs) return;
    int c = y[b];
    const float* g  = gumbel + ((size_t)c * bs + b) * N_COMP;
    const float* lg = logits + c * N_COMP;
    float best = g[0] + lg[0];
    int bi = 0;
    #pragma unroll
    for (int k = 1; k < N_COMP; ++k) {
        float s = g[k] + lg[k];
        if (s > best) { best = s; bi = k; }  // strict > == first-max (jnp.argmax)
    }
    int ck = c * N_COMP + bi;
    ck_arr[b] = ck;
    atomicAdd(&counts[ck], 1);
}

// ---------------- K2: exclusive scan of 100 counts (trivial) ----------------
__global__ __launch_bounds__(64) void k_scan(
    const int* __restrict__ counts, int* __restrict__ offsets, int* __restrict__ cursor)
{
    if (threadIdx.x == 0) {
        int acc = 0;
        for (int i = 0; i < N_CK; ++i) {
            offsets[i] = acc;
            cursor[i] = acc;
            acc += counts[i];
        }
    }
}

// ---------------- K3: scatter sample ids into bucket order ----------------
__global__ __launch_bounds__(256) void k_scatter(
    const int* __restrict__ ck_arr, int* __restrict__ cursor,
    int* __restrict__ order, int bs)
{
    int b = blockIdx.x * 256 + threadIdx.x;
    if (b >= bs) return;
    int pos = atomicAdd(&cursor[ck_arr[b]], 1);
    order[pos] = b;
}

// ---------------- K4: per-bucket batched GEMV ----------------
// grid (100, 2 j-halves, MAXCHUNK), 128 threads.
// Thread tile: 8 j (stride-8) x 4 s. L staged in LDS with per-row column
// rotation (col = (i + 4*jl) & 127) -> conflict-free float4 reads.
// z staged transposed zs[i][sl] -> conflict-free float4 reads over s.
__global__ __launch_bounds__(128) void k_gemm(
    const float* __restrict__ z, const float* __restrict__ m,
    const float* __restrict__ L, const int* __restrict__ counts,
    const int* __restrict__ offsets, const int* __restrict__ order,
    float* __restrict__ out, int bs)
{
    const int ck    = blockIdx.x;
    const int jh    = blockIdx.y;   // 0..1 -> j range [jh*64, jh*64+64)
    const int chunk = blockIdx.z;

    const int n  = counts[ck];
    const int s0 = chunk * TB;
    if (s0 >= n) return;
    const int base = offsets[ck];
    const int ns   = min(TB, n - s0);

    __shared__ float Ls[64 * 128];   // rotated rows: Ls[jl*128 + ((i+4*jl)&127)] = L[jrow][i]
    __shared__ float zs[128 * TB];   // zs[i*TB + sl] = z[sample sl][i]

    const int t = threadIdx.x;

    // ---- stage L half (64 rows x 128 = 2048 float4s, 128 threads x 16) ----
    {
        const float4* Lg4 = (const float4*)(L + (((size_t)ck * N_Z + jh * 64) * N_Z));
        #pragma unroll
        for (int p = 0; p < 16; ++p) {
            int f  = p * 128 + t;      // float4 index in the 64x128 half
            int jl = f >> 5;           // row
            int fi = f & 31;           // float4 within row
            float4 v = Lg4[f];
            int col = ((fi << 2) + 4 * jl) & 127;
            *(float4*)&Ls[jl * 128 + col] = v;
        }
    }
    // ---- stage z transposed ----
    {
        int sl  = t & 63;
        int ih2 = t >> 6;   // 0..1
        int idx = base + s0 + sl;
        if (idx >= bs) idx = bs - 1;          // clamp (padding lanes; results discarded)
        int samp = order[idx];
        const float* zg = z + (size_t)samp * N_Z + ih2 * 64;
        #pragma unroll
        for (int q = 0; q < 16; ++q) {
            float4 v = *(const float4*)(zg + q * 4);
            int i = ih2 * 64 + q * 4;
            zs[(i + 0) * TB + sl] = v.x;
            zs[(i + 1) * TB + sl] = v.y;
            zs[(i + 2) * TB + sl] = v.z;
            zs[(i + 3) * TB + sl] = v.w;
        }
    }
    __syncthreads();

    const int jg = t & 7;     // 8 j-groups, rows jl = jg + 8r
    const int sg = t >> 3;    // 16 s-groups x 4 samples

    float acc[8][4] = {};

    #pragma unroll 2
    for (int i = 0; i < N_Z; i += 4) {
        float4 zv[4];
        #pragma unroll
        for (int ri = 0; ri < 4; ++ri)
            zv[ri] = *(const float4*)&zs[(i + ri) * TB + (sg << 2)];
        #pragma unroll
        for (int r = 0; r < 8; ++r) {
            int jl  = jg + 8 * r;
            int col = (i + 4 * jl) & 127;
            float4 lv = *(const float4*)&Ls[jl * 128 + col];  // L[jrow][i..i+3]
            acc[r][0] += lv.x * zv[0].x + lv.y * zv[1].x + lv.z * zv[2].x + lv.w * zv[3].x;
            acc[r][1] += lv.x * zv[0].y + lv.y * zv[1].y + lv.z * zv[2].y + lv.w * zv[3].y;
            acc[r][2] += lv.x * zv[0].z + lv.y * zv[1].z + lv.z * zv[2].z + lv.w * zv[3].z;
            acc[r][3] += lv.x * zv[0].w + lv.y * zv[1].w + lv.z * zv[2].w + lv.w * zv[3].w;
        }
    }

    // ---- epilogue: add m, scatter to out ----
    #pragma unroll
    for (int r = 0; r < 8; ++r) {
        int j = jh * 64 + jg + 8 * r;
        float mm = m[ck * N_Z + j];
        #pragma unroll
        for (int s = 0; s < 4; ++s) {
            int sl = (sg << 2) + s;
            if (sl < ns) {
                int samp = order[base + s0 + sl];
                out[(size_t)samp * N_Z + j] = acc[r][s] + mm;
            }
        }
    }
}

extern "C" void kernel_launch(void* const* d_in, const int* in_sizes, int n_in,
                              void* d_out, int out_size, void* d_ws, size_t ws_size,
                              hipStream_t stream)
{
    const float* z      = (const float*)d_in[0];
    const int*   y      = (const int*)d_in[1];
    const float* gumbel = (const float*)d_in[2];
    const float* m      = (const float*)d_in[3];
    const float* L      = (const float*)d_in[4];
    const float* logits = (const float*)d_in[5];
    float* out = (float*)d_out;

    const int bs = in_sizes[0] / N_Z;  // 8192

    // workspace layout (ints)
    int* counts  = (int*)d_ws;              // 128
    int* offsets = counts + 128;            // 128
    int* cursor  = offsets + 128;           // 128
    int* ck_arr  = cursor + 128;            // bs
    int* order   = ck_arr + bs;             // bs

    hipMemsetAsync(counts, 0, 128 * sizeof(int), stream);

    k_select<<<(bs + 255) / 256, 256, 0, stream>>>(y, gumbel, logits, ck_arr, counts, bs);
    k_scan<<<1, 64, 0, stream>>>(counts, offsets, cursor);
    k_scatter<<<(bs + 255) / 256, 256, 0, stream>>>(ck_arr, cursor, order, bs);
    k_gemm<<<dim3(N_CK, 2, MAXCHUNK), 128, 0, stream>>>(z, m, L, counts, offsets, order, out, bs);
}

// Round 4
// 99.793 us; speedup vs baseline: 1.4611x; 1.1451x over previous
//
#include <hip/hip_runtime.h>

// Forward collapse:
//   c = y[b]; k = argmax_k(logits[c,k] + gumbel[c,b,k]) (first max)
//   x[b,:] = L[c,k] @ z[b,:] + m[c,k,:]
//
// Round 4: single-pass bucketing (fixed-capacity 256 per ck bucket) removes
// the scan + scatter kernels. Pipeline: memset(512B) -> k_select -> k_gemm.

#define N_Z 128
#define N_COMP 10
#define N_CLASSES 10
#define N_CK (N_CLASSES * N_COMP)
#define CAP 256          // bucket capacity (mean 82, +19 sigma headroom)
#define TB 64            // samples per chunk in gemm kernel
#define MAXCHUNK 4       // CAP / TB

// ---------------- K1: select component + direct bucket append ----------------
__global__ __launch_bounds__(256) void k_select(
    const int* __restrict__ y, const float* __restrict__ gumbel,
    const float* __restrict__ logits, int* __restrict__ counts,
    int* __restrict__ order, int bs)
{
    int b = blockIdx.x * 256 + threadIdx.x;
    if (b >= bs) return;
    int c = y[b];
    const float* g  = gumbel + ((size_t)c * bs + b) * N_COMP;
    const float* lg = logits + c * N_COMP;
    float best = g[0] + lg[0];
    int bi = 0;
    #pragma unroll
    for (int k = 1; k < N_COMP; ++k) {
        float s = g[k] + lg[k];
        if (s > best) { best = s; bi = k; }  // strict > == first-max (jnp.argmax)
    }
    int ck = c * N_COMP + bi;
    int pos = atomicAdd(&counts[ck], 1);
    if (pos < CAP) order[ck * CAP + pos] = b;
}

// ---------------- K2: per-bucket batched GEMV ----------------
// grid (100, 2 j-halves, MAXCHUNK), 128 threads.
// Thread tile: 8 j (stride-8) x 4 s. L staged in LDS with per-row column
// rotation (col = (i + 4*jl) & 127) -> conflict-free float4 reads.
// z staged transposed zs[i][sl] -> conflict-free float4 reads over s.
__global__ __launch_bounds__(128) void k_gemm(
    const float* __restrict__ z, const float* __restrict__ m,
    const float* __restrict__ L, const int* __restrict__ counts,
    const int* __restrict__ order, float* __restrict__ out, int bs)
{
    const int ck    = blockIdx.x;
    const int jh    = blockIdx.y;   // 0..1 -> j range [jh*64, jh*64+64)
    const int chunk = blockIdx.z;

    const int n  = min(counts[ck], CAP);
    const int s0 = chunk * TB;
    if (s0 >= n) return;
    const int ns = min(TB, n - s0);
    const int base = ck * CAP;

    __shared__ float Ls[64 * 128];   // rotated rows: Ls[jl*128 + ((i+4*jl)&127)] = L[jrow][i]
    __shared__ float zs[128 * TB];   // zs[i*TB + sl] = z[sample sl][i]

    const int t = threadIdx.x;

    // ---- stage L half (64 rows x 128 = 2048 float4s, 128 threads x 16) ----
    {
        const float4* Lg4 = (const float4*)(L + (((size_t)ck * N_Z + jh * 64) * N_Z));
        #pragma unroll
        for (int p = 0; p < 16; ++p) {
            int f  = p * 128 + t;      // float4 index in the 64x128 half
            int jl = f >> 5;           // row
            int fi = f & 31;           // float4 within row
            float4 v = Lg4[f];
            int col = ((fi << 2) + 4 * jl) & 127;
            *(float4*)&Ls[jl * 128 + col] = v;
        }
    }
    // ---- stage z transposed ----
    {
        int sl  = t & 63;
        int ih2 = t >> 6;   // 0..1
        int samp = 0;
        if (sl < ns) samp = order[base + s0 + sl];  // padding lanes read sample 0 (discarded)
        const float* zg = z + (size_t)samp * N_Z + ih2 * 64;
        #pragma unroll
        for (int q = 0; q < 16; ++q) {
            float4 v = *(const float4*)(zg + q * 4);
            int i = ih2 * 64 + q * 4;
            zs[(i + 0) * TB + sl] = v.x;
            zs[(i + 1) * TB + sl] = v.y;
            zs[(i + 2) * TB + sl] = v.z;
            zs[(i + 3) * TB + sl] = v.w;
        }
    }
    __syncthreads();

    const int jg = t & 7;     // 8 j-groups, rows jl = jg + 8r
    const int sg = t >> 3;    // 16 s-groups x 4 samples

    float acc[8][4] = {};

    #pragma unroll 2
    for (int i = 0; i < N_Z; i += 4) {
        float4 zv[4];
        #pragma unroll
        for (int ri = 0; ri < 4; ++ri)
            zv[ri] = *(const float4*)&zs[(i + ri) * TB + (sg << 2)];
        #pragma unroll
        for (int r = 0; r < 8; ++r) {
            int jl  = jg + 8 * r;
            int col = (i + 4 * jl) & 127;
            float4 lv = *(const float4*)&Ls[jl * 128 + col];  // L[jrow][i..i+3]
            acc[r][0] += lv.x * zv[0].x + lv.y * zv[1].x + lv.z * zv[2].x + lv.w * zv[3].x;
            acc[r][1] += lv.x * zv[0].y + lv.y * zv[1].y + lv.z * zv[2].y + lv.w * zv[3].y;
            acc[r][2] += lv.x * zv[0].z + lv.y * zv[1].z + lv.z * zv[2].z + lv.w * zv[3].z;
            acc[r][3] += lv.x * zv[0].w + lv.y * zv[1].w + lv.z * zv[2].w + lv.w * zv[3].w;
        }
    }

    // ---- epilogue: add m, scatter to out ----
    #pragma unroll
    for (int r = 0; r < 8; ++r) {
        int j = jh * 64 + jg + 8 * r;
        float mm = m[ck * N_Z + j];
        #pragma unroll
        for (int s = 0; s < 4; ++s) {
            int sl = (sg << 2) + s;
            if (sl < ns) {
                int samp = order[base + s0 + sl];
                out[(size_t)samp * N_Z + j] = acc[r][s] + mm;
            }
        }
    }
}

extern "C" void kernel_launch(void* const* d_in, const int* in_sizes, int n_in,
                              void* d_out, int out_size, void* d_ws, size_t ws_size,
                              hipStream_t stream)
{
    const float* z      = (const float*)d_in[0];
    const int*   y      = (const int*)d_in[1];
    const float* gumbel = (const float*)d_in[2];
    const float* m      = (const float*)d_in[3];
    const float* L      = (const float*)d_in[4];
    const float* logits = (const float*)d_in[5];
    float* out = (float*)d_out;

    const int bs = in_sizes[0] / N_Z;  // 8192

    // workspace layout (ints)
    int* counts = (int*)d_ws;           // 128
    int* order  = counts + 128;         // N_CK * CAP

    hipMemsetAsync(counts, 0, 128 * sizeof(int), stream);
    k_select<<<(bs + 255) / 256, 256, 0, stream>>>(y, gumbel, logits, counts, order, bs);
    k_gemm<<<dim3(N_CK, 2, MAXCHUNK), 128, 0, stream>>>(z, m, L, counts, order, out, bs);
}